// Round 1
// baseline (196.096 us; speedup 1.0000x reference)
//
#include <hip/hip_runtime.h>

#define NPTS  1024
#define NBASIS 8
#define DIM    8
#define HDIM   512
#define CH     16
#define KC     16
#define ROWSB  32

// workspace layout (float offsets)
#define WS_A0   0
#define WS_A0X  (NPTS*HDIM)            // 524288
#define WS_FS   (WS_A0X + HDIM)        // 524800
#define WS_INT  (WS_FS + NPTS*CH)      // 541184
#define WS_MU   (WS_INT + NBASIS*CH)   // 541312
#define WS_BX   (WS_MU + NBASIS)       // 541320

__device__ __forceinline__ float elu(float z) { return z > 0.f ? z : expm1f(z); }

// a0 = elu(s@Wfirst + bfirst), a0x for the single x row, f_s = s@Wf + bf, zero integral accum
__global__ __launch_bounds__(64) void kA(const float* __restrict__ s, const float* __restrict__ x,
    const float* __restrict__ Wfirst, const float* __restrict__ bfirst,
    const float* __restrict__ Wf, const float* __restrict__ bf,
    float* __restrict__ a0, float* __restrict__ a0x, float* __restrict__ f_s,
    float* __restrict__ integral) {
  int m = blockIdx.x;
  int t = threadIdx.x;
  __shared__ float sv[DIM];
  const float* row = (m < NPTS) ? (s + (size_t)m * DIM) : x;
  if (t < DIM) sv[t] = row[t];
  __syncthreads();
  float* o = (m < NPTS) ? (a0 + (size_t)m * HDIM) : a0x;
#pragma unroll
  for (int j = 0; j < HDIM / 64; ++j) {
    int h = t + 64 * j;
    float acc = bfirst[h];
#pragma unroll
    for (int d = 0; d < DIM; ++d) acc += sv[d] * Wfirst[d * HDIM + h];
    o[h] = elu(acc);
  }
  if (m < NPTS) {
    if (t < CH) {
      float acc = bf[t];
#pragma unroll
      for (int d = 0; d < DIM; ++d) acc += sv[d] * Wf[d * CH + t];
      f_s[m * CH + t] = acc;
    }
  } else {
    integral[t] = 0.f;
    integral[t + 64] = 0.f;
  }
}

// main fused kernel: z = a0@Wb[i] (+bb, elu), basis = a1@Wlast (+blast), sum (f_s-basis)^2 over rows
__global__ __launch_bounds__(256, 1) void kB(const float* __restrict__ a0,
    const float* __restrict__ Wb, const float* __restrict__ bb,
    const float* __restrict__ Wlast, const float* __restrict__ blast,
    const float* __restrict__ f_s, float* __restrict__ integral) {
  __shared__ __align__(16) float Alds[KC][36];      // A transposed [k][row], padded
  __shared__ __align__(16) float Blds[KC][HDIM];    // 32 KB; reused as WlT[CH][HDIM] in epilogue
  __shared__ float red[CH];

  int tid = threadIdx.x;
  int i   = blockIdx.x & 7;      // basis index == XCD round-robin -> Wb[i] L2-resident per XCD
  int mt  = blockIdx.x >> 3;     // row tile 0..31
  int rg  = tid >> 5;            // 0..7  (4 rows each)
  int cg  = tid & 31;            // 0..31 (16 cols each: h = 4*cg + 128*j + e)
  int rowbase = mt * ROWSB;
  const float* WbI = Wb + (size_t)i * HDIM * HDIM;

  float acc[4][16];
#pragma unroll
  for (int r = 0; r < 4; ++r)
#pragma unroll
    for (int q = 0; q < 16; ++q) acc[r][q] = 0.f;

  for (int k0 = 0; k0 < HDIM; k0 += KC) {
    __syncthreads();
    // stage A chunk: 32 rows x 16 k, transposed into LDS
#pragma unroll
    for (int it = 0; it < 2; ++it) {
      int idx = tid + 256 * it;
      int kc = idx & 15, r = idx >> 4;
      Alds[kc][r] = a0[(size_t)(rowbase + r) * HDIM + k0 + kc];
    }
    // stage B chunk: 16 k x 512 n (float4-coalesced)
#pragma unroll
    for (int it = 0; it < 8; ++it) {
      int idx = tid + 256 * it;
      int kk = idx >> 7, n4 = idx & 127;
      *(float4*)&Blds[kk][n4 * 4] = *(const float4*)&WbI[(size_t)(k0 + kk) * HDIM + n4 * 4];
    }
    __syncthreads();
#pragma unroll
    for (int kk = 0; kk < KC; ++kk) {
      float4 av = *(const float4*)&Alds[kk][rg * 4];
      float avv[4] = {av.x, av.y, av.z, av.w};
      float4 bv[4];
#pragma unroll
      for (int j = 0; j < 4; ++j) bv[j] = *(const float4*)&Blds[kk][4 * cg + 128 * j];
#pragma unroll
      for (int r = 0; r < 4; ++r) {
        float a = avv[r];
#pragma unroll
        for (int j = 0; j < 4; ++j) {
          acc[r][4 * j + 0] += a * bv[j].x;
          acc[r][4 * j + 1] += a * bv[j].y;
          acc[r][4 * j + 2] += a * bv[j].z;
          acc[r][4 * j + 3] += a * bv[j].w;
        }
      }
    }
  }
  __syncthreads();

  // stage Wlast^T [ch][h] into the (now free) Blds region: 16*512 floats == KC*HDIM exactly
  float* WlT = &Blds[0][0];
#pragma unroll
  for (int it = 0; it < 8; ++it) {
    int idx = tid + 256 * it;            // 2048 float4 of Wlast (512x16)
    int h = idx >> 2, c4 = (idx & 3) * 4;
    float4 v = *(const float4*)&Wlast[h * CH + c4];
    WlT[(c4 + 0) * HDIM + h] = v.x;
    WlT[(c4 + 1) * HDIM + h] = v.y;
    WlT[(c4 + 2) * HDIM + h] = v.z;
    WlT[(c4 + 3) * HDIM + h] = v.w;
  }
  if (tid < CH) red[tid] = 0.f;

  // bias + elu on the accumulator (register-resident)
#pragma unroll
  for (int j = 0; j < 4; ++j) {
    float4 bv = *(const float4*)&bb[i * HDIM + 4 * cg + 128 * j];
    float bvv[4] = {bv.x, bv.y, bv.z, bv.w};
#pragma unroll
    for (int r = 0; r < 4; ++r)
#pragma unroll
      for (int e = 0; e < 4; ++e)
        acc[r][4 * j + e] = elu(acc[r][4 * j + e] + bvv[e]);
  }
  __syncthreads();

  // partial basis projection: p[r][ch] = sum over this thread's 16 h of a1 * Wlast[h][ch]
  float p[4][CH];
#pragma unroll
  for (int r = 0; r < 4; ++r)
#pragma unroll
    for (int ch = 0; ch < CH; ++ch) p[r][ch] = 0.f;
#pragma unroll
  for (int j = 0; j < 4; ++j) {
#pragma unroll
    for (int ch = 0; ch < CH; ++ch) {
      float4 w = *(const float4*)&WlT[ch * HDIM + 4 * cg + 128 * j];
#pragma unroll
      for (int r = 0; r < 4; ++r)
        p[r][ch] += acc[r][4 * j + 0] * w.x + acc[r][4 * j + 1] * w.y +
                    acc[r][4 * j + 2] * w.z + acc[r][4 * j + 3] * w.w;
    }
  }
  // butterfly-reduce over the 32 cg lanes (lane bits 0..4)
#pragma unroll
  for (int r = 0; r < 4; ++r)
#pragma unroll
    for (int ch = 0; ch < CH; ++ch) {
      float v = p[r][ch];
      v += __shfl_xor(v, 1, 64);
      v += __shfl_xor(v, 2, 64);
      v += __shfl_xor(v, 4, 64);
      v += __shfl_xor(v, 8, 64);
      v += __shfl_xor(v, 16, 64);
      p[r][ch] = v;
    }
  if (cg == 0) {
    float sq[CH];
#pragma unroll
    for (int ch = 0; ch < CH; ++ch) sq[ch] = 0.f;
#pragma unroll
    for (int r = 0; r < 4; ++r) {
      int m = rowbase + rg * 4 + r;
#pragma unroll
      for (int ch = 0; ch < CH; ++ch) {
        float basis = p[r][ch] + blast[ch];
        float d = f_s[m * CH + ch] - basis;
        sq[ch] += d * d;
      }
    }
#pragma unroll
    for (int ch = 0; ch < CH; ++ch) atomicAdd(&red[ch], sq[ch]);
  }
  __syncthreads();
  if (tid < CH) atomicAdd(&integral[i * CH + tid], red[tid]);
}

// x-path per basis + mu computation
__global__ __launch_bounds__(256) void kC(const float* __restrict__ a0x,
    const float* __restrict__ Wb, const float* __restrict__ bb,
    const float* __restrict__ Wlast, const float* __restrict__ blast,
    const float* __restrict__ integral, float* __restrict__ mu, float* __restrict__ basisx) {
  int i = blockIdx.x, t = threadIdx.x;
  __shared__ float ax[HDIM];
  __shared__ float wp[4][CH];
  ax[t] = a0x[t];
  ax[t + 256] = a0x[t + 256];
  __syncthreads();
  float p[CH];
#pragma unroll
  for (int ch = 0; ch < CH; ++ch) p[ch] = 0.f;
  for (int hh = 0; hh < 2; ++hh) {
    int h = t + 256 * hh;
    float z = bb[i * HDIM + h];
#pragma unroll 8
    for (int k = 0; k < HDIM; ++k) z += ax[k] * Wb[((size_t)i * HDIM + k) * HDIM + h];
    float a1 = elu(z);
    const float* wl = Wlast + h * CH;
#pragma unroll
    for (int ch = 0; ch < CH; ++ch) p[ch] += a1 * wl[ch];
  }
  int lane = t & 63, w = t >> 6;
#pragma unroll
  for (int ch = 0; ch < CH; ++ch) {
    float v = p[ch];
    v += __shfl_xor(v, 1, 64);
    v += __shfl_xor(v, 2, 64);
    v += __shfl_xor(v, 4, 64);
    v += __shfl_xor(v, 8, 64);
    v += __shfl_xor(v, 16, 64);
    v += __shfl_xor(v, 32, 64);
    if (lane == 0) wp[w][ch] = v;
  }
  __syncthreads();
  if (t < CH)
    basisx[i * CH + t] = wp[0][t] + wp[1][t] + wp[2][t] + wp[3][t] + blast[t];
  if (t == 32) {
    float S = 0.f;
#pragma unroll
    for (int ch = 0; ch < CH; ++ch) S += integral[i * CH + ch];
    float nb = sqrtf(0.25f * S);   // sqrt(VOLUME * sum/NPTS summed over ch) = sqrt(256/1024 * S)
    mu[i] = (nb <= 1000.0f) ? nb : 0.0f;
  }
}

// final combine, replicated over batch
__global__ __launch_bounds__(128) void kD(const float* __restrict__ mu,
    const float* __restrict__ basisx, float* __restrict__ out) {
  int t = threadIdx.x;       // t = b*16 + ch
  int ch = t & 15;
  float num = 0.f, den = 1e-7f;
#pragma unroll
  for (int i = 0; i < NBASIS; ++i) {
    float m = mu[i];
    num += m * basisx[i * CH + ch];
    den += m;
  }
  out[t] = num / den;
}

extern "C" void kernel_launch(void* const* d_in, const int* in_sizes, int n_in,
                              void* d_out, int out_size, void* d_ws, size_t ws_size,
                              hipStream_t stream) {
  const float* s      = (const float*)d_in[0];
  const float* x      = (const float*)d_in[1];
  const float* Wfirst = (const float*)d_in[2];
  const float* bfirst = (const float*)d_in[3];
  const float* Wb     = (const float*)d_in[4];
  const float* bb     = (const float*)d_in[5];
  const float* Wlast  = (const float*)d_in[6];
  const float* blast  = (const float*)d_in[7];
  const float* Wf     = (const float*)d_in[8];
  const float* bf     = (const float*)d_in[9];

  float* ws      = (float*)d_ws;
  float* a0      = ws + WS_A0;
  float* a0x     = ws + WS_A0X;
  float* f_s     = ws + WS_FS;
  float* integral= ws + WS_INT;
  float* mu      = ws + WS_MU;
  float* basisx  = ws + WS_BX;
  float* out     = (float*)d_out;

  kA<<<NPTS + 1, 64, 0, stream>>>(s, x, Wfirst, bfirst, Wf, bf, a0, a0x, f_s, integral);
  kB<<<NBASIS * (NPTS / ROWSB), 256, 0, stream>>>(a0, Wb, bb, Wlast, blast, f_s, integral);
  kC<<<NBASIS, 256, 0, stream>>>(a0x, Wb, bb, Wlast, blast, integral, mu, basisx);
  kD<<<1, 128, 0, stream>>>(mu, basisx, out);
}

// Round 2
// 128.614 us; speedup vs baseline: 1.5247x; 1.5247x over previous
//
#include <hip/hip_runtime.h>

typedef _Float16 half8 __attribute__((ext_vector_type(8)));
typedef float f32x4 __attribute__((ext_vector_type(4)));
typedef float f32x16 __attribute__((ext_vector_type(16)));
typedef unsigned int u32x4 __attribute__((ext_vector_type(4)));

#define NPTS 1024
#define NB 8
#define HDIM 512
#define CH 16
#define RT 1056              // 1024 pts + row 1024 = x + zero pad to 33*32

// workspace byte offsets
#define OFF_WBH 0u
#define OFF_WBL (4u*1024u*1024u)
#define OFF_A0H (8u*1024u*1024u)
#define A0SZ    (64u*RT*8u*2u)            // 1,081,344 B per a0 half array
#define OFF_A0L (OFF_A0H + A0SZ)
#define OFF_WLH (OFF_A0L + A0SZ)
#define OFF_WLL (OFF_WLH + 16384u)
#define OFF_FS  (OFF_WLL + 16384u)
#define OFF_PP  (OFF_FS + 65536u)
#define PPSZ    (8u*2u*RT*16u*4u)         // 1,081,344 B
#define OFF_IP  (OFF_PP + PPSZ)
#define OFF_BX  (OFF_IP + 2048u)

__device__ __forceinline__ float elu(float z) { return z > 0.f ? z : expm1f(z); }

// ---------- kPrep: layout conversions + first layer + f_s ----------
// blocks 0..511  : Wb[i] -> octet hi/lo halves, layout [i*64+koct][n 0..511][8]
// blocks 512..775: a0 rows (4/block): elu(s@Wfirst+b) -> octets [koct][m][8]; f_s
// block 776      : Wlast -> octets [koct][ch][8]
__global__ __launch_bounds__(256) void kPrep(const float* __restrict__ s,
    const float* __restrict__ x, const float* __restrict__ Wfirst,
    const float* __restrict__ bfirst, const float* __restrict__ Wb,
    const float* __restrict__ Wlast, const float* __restrict__ Wf,
    const float* __restrict__ bf,
    _Float16* __restrict__ Wbh, _Float16* __restrict__ Wbl,
    _Float16* __restrict__ WlH, _Float16* __restrict__ WlL,
    _Float16* __restrict__ a0h, _Float16* __restrict__ a0l,
    float* __restrict__ f_s) {
  __shared__ __align__(16) float sm[8192];
  int b = blockIdx.x, t = threadIdx.x;
  if (b < 512) {
    int i = b >> 6, koct = b & 63;
    int j = t >> 5, c = t & 31;
    const float* src = Wb + ((size_t)i * 512 + koct * 8 + j) * 512;
#pragma unroll
    for (int e = 0; e < 4; ++e)
      *(f32x4*)&sm[j * 512 + (e * 32 + c) * 4] = *(const f32x4*)&src[(e * 32 + c) * 4];
    __syncthreads();
#pragma unroll
    for (int p = 0; p < 2; ++p) {
      int n = t + p * 256;
      union { _Float16 h[8]; u32x4 u; } hu, lu;
#pragma unroll
      for (int jj = 0; jj < 8; ++jj) {
        float v = sm[jj * 512 + n];
        _Float16 hv = (_Float16)v;
        hu.h[jj] = hv;
        lu.h[jj] = (_Float16)(v - (float)hv);
      }
      size_t o = ((size_t)(i * 64 + koct) * 512 + n) * 8;
      *(u32x4*)(Wbh + o) = hu.u;
      *(u32x4*)(Wbl + o) = lu.u;
    }
  } else if (b < 776) {
    int rr = t >> 6, tl = t & 63;
    int m = (b - 512) * 4 + rr;
    float* sv = &sm[rr * 8];
    if (tl < 8) sv[tl] = (m < 1024) ? s[m * 8 + tl] : (m == 1024 ? x[tl] : 0.f);
    __syncthreads();
    size_t o = ((size_t)tl * RT + m) * 8;
    if (m <= 1024) {
      float acc[8];
#pragma unroll
      for (int jj = 0; jj < 8; ++jj) acc[jj] = bfirst[8 * tl + jj];
#pragma unroll
      for (int d = 0; d < 8; ++d) {
        float sd = sv[d];
        f32x4 w0 = *(const f32x4*)&Wfirst[d * 512 + 8 * tl];
        f32x4 w1 = *(const f32x4*)&Wfirst[d * 512 + 8 * tl + 4];
#pragma unroll
        for (int e = 0; e < 4; ++e) { acc[e] += sd * w0[e]; acc[4 + e] += sd * w1[e]; }
      }
      union { _Float16 h[8]; u32x4 u; } hu, lu;
#pragma unroll
      for (int jj = 0; jj < 8; ++jj) {
        float v = elu(acc[jj]);
        _Float16 hv = (_Float16)v;
        hu.h[jj] = hv;
        lu.h[jj] = (_Float16)(v - (float)hv);
      }
      *(u32x4*)(a0h + o) = hu.u;
      *(u32x4*)(a0l + o) = lu.u;
      if (m < 1024 && tl < 16) {
        float a = bf[tl];
#pragma unroll
        for (int d = 0; d < 8; ++d) a += sv[d] * Wf[d * 16 + tl];
        f_s[m * 16 + tl] = a;
      }
    } else {
      u32x4 z;
#pragma unroll
      for (int e = 0; e < 4; ++e) z[e] = 0u;
      *(u32x4*)(a0h + o) = z;
      *(u32x4*)(a0l + o) = z;
    }
  } else {
#pragma unroll
    for (int it = 0; it < 32; ++it) sm[t + 256 * it] = Wlast[t + 256 * it];
    __syncthreads();
#pragma unroll
    for (int p = 0; p < 4; ++p) {
      int oi = p * 256 + t;
      int ko = oi >> 4, ch = oi & 15;
      union { _Float16 h[8]; u32x4 u; } hu, lu;
#pragma unroll
      for (int jj = 0; jj < 8; ++jj) {
        float v = sm[(ko * 8 + jj) * 16 + ch];
        _Float16 hv = (_Float16)v;
        hu.h[jj] = hv;
        lu.h[jj] = (_Float16)(v - (float)hv);
      }
      *(u32x4*)(WlH + oi * 8) = hu.u;
      *(u32x4*)(WlL + oi * 8) = lu.u;
    }
  }
}

// ---------- kB: split-f16 MFMA GEMM + elu + Wlast projection ----------
// grid 528 = i(8, ==XCD) x mt(33, 32 rows) x nh(2, 256 cols). Wave w owns 64 cols.
// B fragments read straight from L2 (no K-loop barriers); A tile staged in LDS once.
__global__ __launch_bounds__(256, 2) void kB(const _Float16* __restrict__ Wbh,
    const _Float16* __restrict__ Wbl, const _Float16* __restrict__ a0h,
    const _Float16* __restrict__ a0l, const _Float16* __restrict__ WlH,
    const _Float16* __restrict__ WlL, const float* __restrict__ bb,
    float* __restrict__ Pp) {
  __shared__ u32x4 AH[2048];   // 32KB: A-hi octets [koct][m]; epilogue: per-wave a1 scratch
  __shared__ u32x4 AL[2048];   // 32KB: A-lo
  __shared__ float S2[32][16];
  int t = threadIdx.x, b = blockIdx.x;
  int i = b & 7, r2 = b >> 3;
  int nh = r2 & 1, mt = r2 >> 1;
  int m0 = mt * 32, nb0 = nh * 256;
  int w = t >> 6, lane = t & 63, ln = lane & 31, q = lane >> 5, q4 = lane >> 4;

  const u32x4* a0h4 = (const u32x4*)a0h;
  const u32x4* a0l4 = (const u32x4*)a0l;
#pragma unroll
  for (int it = 0; it < 8; ++it) {
    int o = t + 256 * it;
    size_t g = (size_t)(o >> 5) * RT + m0 + (o & 31);
    AH[o] = a0h4[g];
    AL[o] = a0l4[g];
  }
  __syncthreads();

  int nwb = nb0 + w * 64;
  const u32x4* bh4 = (const u32x4*)Wbh;
  const u32x4* bl4 = (const u32x4*)Wbl;
  f32x16 hh0, hh1, hl0, hl1, lh0, lh1;
#pragma unroll
  for (int r = 0; r < 16; ++r) { hh0[r]=0.f; hh1[r]=0.f; hl0[r]=0.f; hl1[r]=0.f; lh0[r]=0.f; lh1[r]=0.f; }

#pragma unroll 4
  for (int ks = 0; ks < 32; ++ks) {
    int koct = ks * 2 + q;
    half8 aH = __builtin_bit_cast(half8, AH[koct * 32 + ln]);
    half8 aL = __builtin_bit_cast(half8, AL[koct * 32 + ln]);
    size_t bo = ((size_t)(i * 64 + koct)) * 512 + nwb + ln;
    half8 bH0 = __builtin_bit_cast(half8, bh4[bo]);
    half8 bH1 = __builtin_bit_cast(half8, bh4[bo + 32]);
    half8 bL0 = __builtin_bit_cast(half8, bl4[bo]);
    half8 bL1 = __builtin_bit_cast(half8, bl4[bo + 32]);
    hh0 = __builtin_amdgcn_mfma_f32_32x32x16_f16(aH, bH0, hh0, 0, 0, 0);
    hh1 = __builtin_amdgcn_mfma_f32_32x32x16_f16(aH, bH1, hh1, 0, 0, 0);
    hl0 = __builtin_amdgcn_mfma_f32_32x32x16_f16(aH, bL0, hl0, 0, 0, 0);
    hl1 = __builtin_amdgcn_mfma_f32_32x32x16_f16(aH, bL1, hl1, 0, 0, 0);
    lh0 = __builtin_amdgcn_mfma_f32_32x32x16_f16(aL, bH0, lh0, 0, 0, 0);
    lh1 = __builtin_amdgcn_mfma_f32_32x32x16_f16(aL, bH1, lh1, 0, 0, 0);
  }

  float zv[2][16];
#pragma unroll
  for (int r = 0; r < 16; ++r) {
    zv[0][r] = hh0[r] + hl0[r] + lh0[r];
    zv[1][r] = hh1[r] + hl1[r] + lh1[r];
  }
  __syncthreads();                       // all A-tile reads done; region reusable
  for (int o = t; o < 512; o += 256) ((float*)S2)[o] = 0.f;

  _Float16* scrH = (_Float16*)&AH[w * 512];
  _Float16* scrL = (_Float16*)&AH[w * 512 + 256];
#pragma unroll
  for (int nt = 0; nt < 2; ++nt)
#pragma unroll
    for (int r = 0; r < 16; ++r) {
      int row = (r & 3) + 8 * (r >> 2) + 4 * q;   // 32x32 C-layout row
      int kl = nt * 32 + ln;                      // local h 0..63
      int h = nb0 + w * 64 + kl;
      float a1 = elu(zv[nt][r] + bb[i * 512 + h]);
      _Float16 hv = (_Float16)a1;
      _Float16 lv = (_Float16)(a1 - (float)hv);
      int oi = (row >> 4) * 128 + (kl >> 3) * 16 + (row & 15);
      scrH[oi * 8 + (kl & 7)] = hv;
      scrL[oi * 8 + (kl & 7)] = lv;
    }
  __syncthreads();                       // S2 zeroed + scr written

  int hb8 = (nb0 + w * 64) >> 3;
  const u32x4* wh4 = (const u32x4*)WlH;
  const u32x4* wl4 = (const u32x4*)WlL;
  const u32x4* sH4 = &AH[w * 512];
  const u32x4* sL4 = &AH[w * 512 + 256];
#pragma unroll
  for (int mt2 = 0; mt2 < 2; ++mt2) {
    f32x4 D2;
#pragma unroll
    for (int r = 0; r < 4; ++r) D2[r] = 0.f;
#pragma unroll
    for (int ks2 = 0; ks2 < 2; ++ks2) {
      int ai = mt2 * 128 + (ks2 * 4 + q4) * 16 + (lane & 15);
      half8 pH = __builtin_bit_cast(half8, sH4[ai]);
      half8 pL = __builtin_bit_cast(half8, sL4[ai]);
      size_t wo = (size_t)(hb8 + ks2 * 4 + q4) * 16 + (lane & 15);
      half8 wH = __builtin_bit_cast(half8, wh4[wo]);
      half8 wL = __builtin_bit_cast(half8, wl4[wo]);
      D2 = __builtin_amdgcn_mfma_f32_16x16x32_f16(pH, wH, D2, 0, 0, 0);
      D2 = __builtin_amdgcn_mfma_f32_16x16x32_f16(pH, wL, D2, 0, 0, 0);
      D2 = __builtin_amdgcn_mfma_f32_16x16x32_f16(pL, wH, D2, 0, 0, 0);
    }
#pragma unroll
    for (int r = 0; r < 4; ++r)
      atomicAdd(&S2[mt2 * 16 + q4 * 4 + r][lane & 15], D2[r]);
  }
  __syncthreads();
  for (int o = t; o < 512; o += 256) {
    int m = o >> 4, ch = o & 15;
    Pp[((size_t)(i * 2 + nh) * RT + m0 + m) * 16 + ch] = S2[m][ch];
  }
}

// ---------- kTail: diff^2 reduction + basisx ----------
__global__ __launch_bounds__(256) void kTail(const float* __restrict__ Pp,
    const float* __restrict__ f_s, const float* __restrict__ blast,
    float* __restrict__ Ipart, float* __restrict__ basisx) {
  __shared__ float R[16][16];
  int b = blockIdx.x, t = threadIdx.x;
  if (b < 32) {
    int i = b >> 2, mq = b & 3;
    int ch = t & 15, g = t >> 4;
    float bl = blast[ch];
    const float* P0 = Pp + (size_t)(i * 2) * RT * 16;
    const float* P1 = Pp + (size_t)(i * 2 + 1) * RT * 16;
    float loc = 0.f;
#pragma unroll
    for (int it = 0; it < 16; ++it) {
      int m = mq * 256 + g + 16 * it;
      float bs = P0[m * 16 + ch] + P1[m * 16 + ch] + bl;
      float d = f_s[m * 16 + ch] - bs;
      loc += d * d;
    }
    R[g][ch] = loc;
    __syncthreads();
    if (t < 16) {
      float ssum = 0.f;
#pragma unroll
      for (int gg = 0; gg < 16; ++gg) ssum += R[gg][t];
      Ipart[(i * 4 + mq) * 16 + t] = ssum;
    }
  } else if (t < 128) {
    int i = t >> 4, ch = t & 15;
    basisx[t] = Pp[((size_t)(i * 2) * RT + 1024) * 16 + ch]
              + Pp[((size_t)(i * 2 + 1) * RT + 1024) * 16 + ch] + blast[ch];
  }
}

// ---------- kFin: mu + weighted combine ----------
__global__ __launch_bounds__(128) void kFin(const float* __restrict__ Ipart,
    const float* __restrict__ basisx, float* __restrict__ out) {
  __shared__ float muL[8];
  int t = threadIdx.x;
  if (t < 8) {
    float S = 0.f;
#pragma unroll
    for (int qq = 0; qq < 64; ++qq) S += Ipart[t * 64 + qq];
    float nb = 0.5f * sqrtf(S);   // sqrt(VOLUME * mean summed over ch) = sqrt(S/4)
    muL[t] = (nb <= 1000.0f) ? nb : 0.f;
  }
  __syncthreads();
  int ch = t & 15;
  float num = 0.f, den = 1e-7f;
#pragma unroll
  for (int i = 0; i < NB; ++i) {
    num += muL[i] * basisx[i * 16 + ch];
    den += muL[i];
  }
  out[t] = num / den;
}

extern "C" void kernel_launch(void* const* d_in, const int* in_sizes, int n_in,
                              void* d_out, int out_size, void* d_ws, size_t ws_size,
                              hipStream_t stream) {
  const float* s      = (const float*)d_in[0];
  const float* x      = (const float*)d_in[1];
  const float* Wfirst = (const float*)d_in[2];
  const float* bfirst = (const float*)d_in[3];
  const float* Wb     = (const float*)d_in[4];
  const float* bb     = (const float*)d_in[5];
  const float* Wlast  = (const float*)d_in[6];
  const float* blast  = (const float*)d_in[7];
  const float* Wf     = (const float*)d_in[8];
  const float* bf     = (const float*)d_in[9];

  char* ws = (char*)d_ws;
  _Float16* Wbh = (_Float16*)(ws + OFF_WBH);
  _Float16* Wbl = (_Float16*)(ws + OFF_WBL);
  _Float16* a0h = (_Float16*)(ws + OFF_A0H);
  _Float16* a0l = (_Float16*)(ws + OFF_A0L);
  _Float16* WlH = (_Float16*)(ws + OFF_WLH);
  _Float16* WlL = (_Float16*)(ws + OFF_WLL);
  float* f_s    = (float*)(ws + OFF_FS);
  float* Pp     = (float*)(ws + OFF_PP);
  float* Ipart  = (float*)(ws + OFF_IP);
  float* basisx = (float*)(ws + OFF_BX);
  float* out    = (float*)d_out;

  kPrep<<<777, 256, 0, stream>>>(s, x, Wfirst, bfirst, Wb, Wlast, Wf, bf,
                                 Wbh, Wbl, WlH, WlL, a0h, a0l, f_s);
  kB<<<528, 256, 0, stream>>>(Wbh, Wbl, a0h, a0l, WlH, WlL, bb, Pp);
  kTail<<<33, 256, 0, stream>>>(Pp, f_s, blast, Ipart, basisx);
  kFin<<<1, 128, 0, stream>>>(Ipart, basisx, out);
}